// Round 11
// baseline (360.922 us; speedup 1.0000x reference)
//
#include <hip/hip_runtime.h>
#include <cmath>

#define B_   64
#define LX_  1024
#define LY_  1024
#define D_   300
#define DP   320      // padded K / e dimension
#define DV   304      // padded d for PV (19 * 16)
#define BM   128      // s-tile rows per block (8 waves x 16)
#define KV   32       // t-tile
#define NT   (LY_ / KV)

using f32x4  = __attribute__((ext_vector_type(4))) float;
using bf16x8 = __attribute__((ext_vector_type(8))) __bf16;
using u32x4  = __attribute__((ext_vector_type(4))) unsigned int;
using u32x2  = __attribute__((ext_vector_type(2))) unsigned int;

static __device__ __forceinline__ unsigned short f2b(float f){
    unsigned u = __builtin_bit_cast(unsigned, f);
    u += 0x7FFFu + ((u >> 16) & 1u);          // round-to-nearest-even
    return (unsigned short)(u >> 16);
}

static __device__ __forceinline__ unsigned pk_bf16(float lo, float hi){
    unsigned r;
    asm volatile("v_cvt_pk_bf16_f32 %0, %1, %2" : "=v"(r) : "v"(lo), "v"(hi));
    return r;
}

static __device__ __forceinline__ bf16x8 ld_bf8(const unsigned short* p){
    u32x4 u = *(const u32x4*)p;
    return __builtin_bit_cast(bf16x8, u);
}

static __device__ __forceinline__ f32x4 mfma16(bf16x8 a, bf16x8 b, f32x4 c){
    return __builtin_amdgcn_mfma_f32_16x16x32_bf16(a, b, c, 0, 0, 0);
}

// async global->LDS DMA, 16B/lane; LDS dest = wave-uniform base + lane*16
static __device__ __forceinline__ void gload16(const unsigned short* g, unsigned short* l){
    __builtin_amdgcn_global_load_lds(
        (const __attribute__((address_space(1))) void*)g,
        (__attribute__((address_space(3))) void*)l, 16, 0, 0);
}

// ---------------- K0: W (300x300 f32) -> Wb (320x320 bf16, zero padded) ----
__global__ void k_wconv(const float* __restrict__ W, unsigned short* __restrict__ Wb){
    int i = blockIdx.x * 256 + threadIdx.x;
    if (i >= DP * DP) return;
    int e = i / DP, d = i % DP;
    float v = (e < D_ && d < D_) ? W[e * D_ + d] : 0.f;
    Wb[i] = f2b(v);
}

// ---------------- K2: y (b,t,d f32) -> yT (b,d,t bf16), d padded to 304 ----
__global__ __launch_bounds__(256) void k_ytrans(const float* __restrict__ Y,
                                                unsigned short* __restrict__ yT){
    __shared__ float tile[64][65];
    const int bid = blockIdx.x;           // 64 * 16 * 5
    const int b  = bid / 80;
    const int tt = (bid % 80) / 5;
    const int dt = bid % 5;
    const int t0 = tt * 64, d0 = dt * 64;
    const int tid = threadIdx.x;
    const int dl = tid & 63, qq = tid >> 6;
    #pragma unroll
    for (int r = 0; r < 16; ++r){
        const int tl = qq * 16 + r;
        const int d = d0 + dl;
        float v = (d < D_) ? Y[((long)b * LY_ + t0 + tl) * D_ + d] : 0.f;
        tile[tl][dl] = v;
    }
    __syncthreads();
    #pragma unroll
    for (int r = 0; r < 16; ++r){
        const int drow = d0 + qq * 16 + r;
        if (drow < DV){
            float v = (drow < D_) ? tile[dl][qq * 16 + r] : 0.f;
            yT[((long)b * DV + drow) * LY_ + t0 + dl] = f2b(v);
        }
    }
}

// ---------------- K1: proj = relu(Z @ W^T + b), swapped-operand epilogue ----
__global__ __launch_bounds__(256) void k_proj(const float* __restrict__ X,
        const float* __restrict__ Y, const float* __restrict__ bias,
        const unsigned short* __restrict__ Wb,
        unsigned short* __restrict__ Px, unsigned short* __restrict__ Py){
    const int tid = threadIdx.x;
    const int w = tid >> 6, l = tid & 63;
    const int lr = l & 15, lg = l >> 4;
    const long m0 = (long)blockIdx.x * 128;
    const bool isX = (m0 < (long)B_ * LX_);
    const float* S = isX ? X : Y;
    unsigned short* Dst = isX ? Px : Py;
    const long base = isX ? m0 : m0 - (long)B_ * LX_;

    u32x4 a[2][10];
    #pragma unroll
    for (int ms = 0; ms < 2; ++ms){
        const float* rp = S + (base + 32 * w + 16 * ms + lr) * D_;
        #pragma unroll
        for (int ks = 0; ks < 10; ++ks){
            const int k0 = ks * 32 + lg * 8;
            f32x4 v0 = {0,0,0,0}, v1 = {0,0,0,0};
            if (k0 + 4 <= D_) v0 = *(const f32x4*)(rp + k0);
            if (k0 + 8 <= D_) v1 = *(const f32x4*)(rp + k0 + 4);
            u32x4 u;
            u[0] = pk_bf16(v0[0], v0[1]);
            u[1] = pk_bf16(v0[2], v0[3]);
            u[2] = pk_bf16(v1[0], v1[1]);
            u[3] = pk_bf16(v1[2], v1[3]);
            a[ms][ks] = u;
        }
    }

    #pragma unroll 2
    for (int es = 0; es < 20; ++es){
        f32x4 acc0 = {0,0,0,0}, acc1 = {0,0,0,0};
        const unsigned short* wp = Wb + (es * 16 + lr) * DP + lg * 8;
        #pragma unroll
        for (int ks = 0; ks < 10; ++ks){
            bf16x8 bf = ld_bf8(wp + ks * 32);       // A: row=e, k=d
            acc0 = mfma16(bf, __builtin_bit_cast(bf16x8, a[0][ks]), acc0);
            acc1 = mfma16(bf, __builtin_bit_cast(bf16x8, a[1][ks]), acc1);
        }
        // lane holds D[e = es*16 + 4*lg + r][m = lr]
        const int e0 = es * 16 + lg * 4;
        f32x4 bv = {0,0,0,0};
        if (e0 + 4 <= D_) bv = *(const f32x4*)(bias + e0);
        else {
            #pragma unroll
            for (int r = 0; r < 4; ++r) bv[r] = (e0 + r < D_) ? bias[e0 + r] : 0.f;
        }
        float s0[4], s1[4];
        #pragma unroll
        for (int r = 0; r < 4; ++r){
            float t0v = acc0[r] + bv[r]; s0[r] = t0v > 0.f ? t0v : 0.f;
            float t1v = acc1[r] + bv[r]; s1[r] = t1v > 0.f ? t1v : 0.f;
        }
        const u32x2 o0 = { pk_bf16(s0[0], s0[1]), pk_bf16(s0[2], s0[3]) };
        const u32x2 o1 = { pk_bf16(s1[0], s1[1]), pk_bf16(s1[2], s1[3]) };
        *(u32x2*)(Dst + (base + 32 * w + lr) * DP + e0)      = o0;
        *(u32x2*)(Dst + (base + 32 * w + 16 + lr) * DP + e0) = o1;
    }
}

// ---------------- K3: flash attention, 512-thread block, dbuf DMA -----------
// 1 block/CU (LDS 90KB) = 8 waves = 2/SIMD. launch_bounds arg2=1 so the
// VGPR cap is 256 (empirical rule: cap = 256/arg2; arg2=2 capped at 128 and
// spilled 30MB in r10). Residency is unchanged: LDS already limits to 1 block.
__global__ __launch_bounds__(512, 1) void k_attn(const int* __restrict__ mask,
        const unsigned short* __restrict__ Px, const unsigned short* __restrict__ Py,
        const unsigned short* __restrict__ yT, float* __restrict__ out){
    __shared__ unsigned short YpL[2][KV][320];   // linear, DMA-written
    __shared__ unsigned short yTL[2][DV][32];    // linear, DMA-written
    __shared__ unsigned short PL[BM][40];        // ds-written (padded stride)

    const int tid = threadIdx.x;
    const int w = tid >> 6, l = tid & 63;        // 8 waves
    const int lr = l & 15, lg = l >> 4;
    const int sw3 = lr & 7;          // Yp read swizzle: chunk ^= sw3
    const int s2  = (lr >> 1) & 3;   // yT read swizzle: chunk ^= s2

    // XCD swizzle: 8 s-blocks of a batch stay on one XCD
    const int bid = blockIdx.x;              // 512
    const int xcd = bid & 7;
    const int g = bid >> 3;                  // 0..63
    const int b = xcd + 8 * (g >> 3);
    const int s0 = (g & 7) * BM;

    // Q fragments: wave w owns rows s0+16w .. s0+16w+15
    u32x4 q[10];
    {
        const unsigned short* qp = Px + ((long)b * LX_ + s0 + 16 * w + lr) * DP + lg * 8;
        #pragma unroll
        for (int ks = 0; ks < 10; ++ks) q[ks] = *(const u32x4*)(qp + ks * 32);
    }

    // per-lane PRE-SWIZZLED global source pointers (tile 0; advance per iter)
    // Yp: 1280 chunks of 16B; tid, tid+512, 1024+tid(<256)
    const unsigned short* srcYp0;
    const unsigned short* srcYp1;
    const unsigned short* srcYp2;
    {
        int id;
        id = tid;                { int r_ = id / 40, c_ = id % 40; srcYp0 = Py + ((long)b * LY_ + r_) * DP + ((c_ ^ (r_ & 7)) << 3); }
        id = tid + 512;          { int r_ = id / 40, c_ = id % 40; srcYp1 = Py + ((long)b * LY_ + r_) * DP + ((c_ ^ (r_ & 7)) << 3); }
        id = 1024 + (tid & 255); { int r_ = id / 40, c_ = id % 40; srcYp2 = Py + ((long)b * LY_ + r_) * DP + ((c_ ^ (r_ & 7)) << 3); }
    }
    // yT: 1216 chunks; tid, tid+512, 1024+tid(<192)
    const unsigned short* srcYT0;
    const unsigned short* srcYT1;
    const unsigned short* srcYT2;
    {
        int id;
        id = tid;                          { int r_ = id >> 2, c_ = id & 3; srcYT0 = yT + ((long)b * DV + r_) * LY_ + ((c_ ^ ((r_ >> 1) & 3)) << 3); }
        id = tid + 512;                    { int r_ = id >> 2, c_ = id & 3; srcYT1 = yT + ((long)b * DV + r_) * LY_ + ((c_ ^ ((r_ >> 1) & 3)) << 3); }
        id = (tid < 192) ? 1024 + tid : 1215; { int r_ = id >> 2, c_ = id & 3; srcYT2 = yT + ((long)b * DV + r_) * LY_ + ((c_ ^ ((r_ >> 1) & 3)) << 3); }
    }

#define STAGE(NXT) do { \
        gload16(srcYp0, &YpL[NXT][0][0] + w * 512); \
        gload16(srcYp1, &YpL[NXT][0][0] + 4096 + w * 512); \
        if (w < 4) gload16(srcYp2, &YpL[NXT][0][0] + 8192 + w * 512); \
        gload16(srcYT0, &yTL[NXT][0][0] + w * 512); \
        gload16(srcYT1, &yTL[NXT][0][0] + 4096 + w * 512); \
        if (w < 3) gload16(srcYT2, &yTL[NXT][0][0] + 8192 + w * 512); \
    } while (0)
#define ADV() do { \
        srcYp0 += KV * DP; srcYp1 += KV * DP; srcYp2 += KV * DP; \
        srcYT0 += KV; srcYT1 += KV; srcYT2 += KV; \
    } while (0)

    const int* mrow = mask + (long)b * LY_;

    // ---- prologue: stage tile 0 into buf0; masks for tiles 0 and 1 ----
    STAGE(0); ADV();
    int4 mc0 = *(const int4*)(mrow + lg * 4);
    int4 mc1 = *(const int4*)(mrow + 16 + lg * 4);
    int4 mn0 = *(const int4*)(mrow + KV + lg * 4);
    int4 mn1 = *(const int4*)(mrow + KV + 16 + lg * 4);
    asm volatile("s_waitcnt vmcnt(0)" ::: "memory");
    __syncthreads();

    f32x4 acc[19];
    #pragma unroll
    for (int n = 0; n < 19; ++n) acc[n] = f32x4{0,0,0,0};
    float m_r = -INFINITY;    // running max for s-row = s0+16w+lr
    float l_r = 0.f;

#define BODY(IT, CUR, NXT) { \
        const int it = (IT); \
        /* prefetch mask for tile it+2 (used next iteration, no wait here) */ \
        const int itn = (it + 2 < NT) ? (it + 2) : (NT - 1); \
        const int4 mf0 = *(const int4*)(mrow + itn * KV + lg * 4); \
        const int4 mf1 = *(const int4*)(mrow + itn * KV + 16 + lg * 4); \
        /* DMA tile it+1 -> other buffer (decision from pre-loaded mn) */ \
        if (it < NT - 1){ \
            const int nall = (mn0.x && mn0.y && mn0.z && mn0.w && \
                              mn1.x && mn1.y && mn1.z && mn1.w) ? 1 : 0; \
            if (!__all(nall)) STAGE(NXT); \
        } \
        ADV(); \
        /* compute tile it from CUR buffer */ \
        const int allm = (mc0.x && mc0.y && mc0.z && mc0.w && \
                          mc1.x && mc1.y && mc1.z && mc1.w) ? 1 : 0; \
        if (!__all(allm)){ \
            const unsigned short* YpC = &YpL[CUR][0][0]; \
            const unsigned short* yTC = &yTL[CUR][0][0]; \
            f32x4 sv0 = {0,0,0,0}, sv1 = {0,0,0,0}; \
            _Pragma("unroll") \
            for (int ks = 0; ks < 10; ++ks){ \
                const int cc = (((ks << 2) | lg) ^ sw3) << 3; \
                bf16x8 qf = __builtin_bit_cast(bf16x8, q[ks]); \
                bf16x8 a0 = ld_bf8(YpC + lr * 320 + cc); \
                bf16x8 a1 = ld_bf8(YpC + (16 + lr) * 320 + cc); \
                sv0 = mfma16(a0, qf, sv0); \
                sv1 = mfma16(a1, qf, sv1); \
            } \
            float v0[4], v1[4]; \
            v0[0] = sv0[0] + (mc0.x ? -3.0e38f : 0.f); \
            v0[1] = sv0[1] + (mc0.y ? -3.0e38f : 0.f); \
            v0[2] = sv0[2] + (mc0.z ? -3.0e38f : 0.f); \
            v0[3] = sv0[3] + (mc0.w ? -3.0e38f : 0.f); \
            v1[0] = sv1[0] + (mc1.x ? -3.0e38f : 0.f); \
            v1[1] = sv1[1] + (mc1.y ? -3.0e38f : 0.f); \
            v1[2] = sv1[2] + (mc1.z ? -3.0e38f : 0.f); \
            v1[3] = sv1[3] + (mc1.w ? -3.0e38f : 0.f); \
            float mx = fmaxf(fmaxf(fmaxf(v0[0], v0[1]), fmaxf(v0[2], v0[3])), \
                             fmaxf(fmaxf(v1[0], v1[1]), fmaxf(v1[2], v1[3]))); \
            mx = fmaxf(mx, __shfl_xor(mx, 16)); \
            mx = fmaxf(mx, __shfl_xor(mx, 32)); \
            float p0[4], p1[4], ps = 0.f; \
            if (__all(mx <= m_r + 6.0f)){ \
                _Pragma("unroll") \
                for (int r = 0; r < 4; ++r){ \
                    p0[r] = __expf(v0[r] - m_r); \
                    p1[r] = __expf(v1[r] - m_r); \
                    ps += p0[r] + p1[r]; \
                } \
                ps += __shfl_xor(ps, 16); \
                ps += __shfl_xor(ps, 32); \
                l_r += ps; \
            } else { \
                const float nm = fmaxf(m_r, mx); \
                _Pragma("unroll") \
                for (int r = 0; r < 4; ++r){ \
                    p0[r] = __expf(v0[r] - nm); \
                    p1[r] = __expf(v1[r] - nm); \
                    ps += p0[r] + p1[r]; \
                } \
                ps += __shfl_xor(ps, 16); \
                ps += __shfl_xor(ps, 32); \
                const float sc = __expf(m_r - nm); \
                l_r = l_r * sc + ps; \
                m_r = nm; \
                float scr[4]; \
                _Pragma("unroll") \
                for (int r = 0; r < 4; ++r) scr[r] = __shfl(sc, lg * 4 + r); \
                _Pragma("unroll") \
                for (int n = 0; n < 19; ++n){ \
                    _Pragma("unroll") \
                    for (int r = 0; r < 4; ++r) acc[n][r] *= scr[r]; \
                } \
            } \
            const unsigned c00 = pk_bf16(p0[0], p0[1]); \
            const unsigned c01 = pk_bf16(p0[2], p0[3]); \
            const unsigned c10 = pk_bf16(p1[0], p1[1]); \
            const unsigned c11 = pk_bf16(p1[2], p1[3]); \
            *(u32x2*)&PL[16 * w + lr][4 * lg]      = u32x2{c00, c01}; \
            *(u32x2*)&PL[16 * w + lr][16 + 4 * lg] = u32x2{c10, c11}; \
            bf16x8 pf = ld_bf8(&PL[16 * w + lr][lg * 8]); \
            const int vcc = (lg ^ s2) << 3; \
            _Pragma("unroll") \
            for (int n = 0; n < 19; ++n){ \
                bf16x8 vf = ld_bf8(yTC + (n * 16 + lr) * 32 + vcc); \
                acc[n] = mfma16(pf, vf, acc[n]); \
            } \
        } \
        asm volatile("s_waitcnt vmcnt(0)" ::: "memory"); \
        __syncthreads(); \
        mc0 = mn0; mc1 = mn1; mn0 = mf0; mn1 = mf1; \
    }

    for (int itp = 0; itp < NT; itp += 2){
        BODY(itp,     0, 1)
        BODY(itp + 1, 1, 0)
    }
#undef BODY
#undef STAGE
#undef ADV

    // normalize: 1/l for rows s = 4*lg + r via broadcast
    const float il = 1.f / l_r;
    float invr[4];
    #pragma unroll
    for (int r = 0; r < 4; ++r) invr[r] = __shfl(il, lg * 4 + r);

    #pragma unroll
    for (int n = 0; n < 19; ++n){
        const int d = n * 16 + lr;
        if (d < D_){
            #pragma unroll
            for (int r = 0; r < 4; ++r){
                out[((long)b * LX_ + s0 + 16 * w + lg * 4 + r) * D_ + d] = acc[n][r] * invr[r];
            }
        }
    }
}

extern "C" void kernel_launch(void* const* d_in, const int* in_sizes, int n_in,
                              void* d_out, int out_size, void* d_ws, size_t ws_size,
                              hipStream_t stream){
    const float* x = (const float*)d_in[0];
    const float* y = (const float*)d_in[1];
    const int* ymask = (const int*)d_in[2];
    const float* W = (const float*)d_in[3];
    const float* bias = (const float*)d_in[4];
    float* out = (float*)d_out;

    unsigned short* Wb  = (unsigned short*)d_ws;
    unsigned short* Px  = (unsigned short*)((char*)d_ws + (1 << 18));
    unsigned short* Py  = (unsigned short*)((char*)d_ws + (1 << 18) + 41943040LL);
    unsigned short* yTw = (unsigned short*)((char*)d_ws + (1 << 18) + 83886080LL);

    hipLaunchKernelGGL(k_wconv, dim3((DP * DP + 255) / 256), dim3(256), 0, stream, W, Wb);
    hipLaunchKernelGGL(k_proj,  dim3(1024), dim3(256), 0, stream, x, y, bias, Wb, Px, Py);
    hipLaunchKernelGGL(k_ytrans, dim3(64 * 80), dim3(256), 0, stream, y, yTw);
    hipLaunchKernelGGL(k_attn,  dim3(512), dim3(512), 0, stream, ymask, Px, Py, yTw, out);
}

// Round 12
// 303.085 us; speedup vs baseline: 1.1908x; 1.1908x over previous
//
#include <hip/hip_runtime.h>
#include <cmath>

#define B_   64
#define LX_  1024
#define LY_  1024
#define D_   300
#define DP   320      // padded K / e dimension
#define DV   304      // padded d for PV (19 * 16)
#define BM   64       // s-tile rows per block (flash attn)
#define KV   32       // t-tile
#define NT   (LY_ / KV)

using f32x4  = __attribute__((ext_vector_type(4))) float;
using bf16x8 = __attribute__((ext_vector_type(8))) __bf16;
using u32x4  = __attribute__((ext_vector_type(4))) unsigned int;
using u32x2  = __attribute__((ext_vector_type(2))) unsigned int;

static __device__ __forceinline__ unsigned short f2b(float f){
    unsigned u = __builtin_bit_cast(unsigned, f);
    u += 0x7FFFu + ((u >> 16) & 1u);          // round-to-nearest-even
    return (unsigned short)(u >> 16);
}

static __device__ __forceinline__ unsigned pk_bf16(float lo, float hi){
    unsigned r;
    asm volatile("v_cvt_pk_bf16_f32 %0, %1, %2" : "=v"(r) : "v"(lo), "v"(hi));
    return r;
}

static __device__ __forceinline__ bf16x8 ld_bf8(const unsigned short* p){
    u32x4 u = *(const u32x4*)p;
    return __builtin_bit_cast(bf16x8, u);
}

static __device__ __forceinline__ f32x4 mfma16(bf16x8 a, bf16x8 b, f32x4 c){
    return __builtin_amdgcn_mfma_f32_16x16x32_bf16(a, b, c, 0, 0, 0);
}

// ---------------- K0: W (300x300 f32) -> Wb (320x320 bf16, zero padded) ----
__global__ void k_wconv(const float* __restrict__ W, unsigned short* __restrict__ Wb){
    int i = blockIdx.x * 256 + threadIdx.x;
    if (i >= DP * DP) return;
    int e = i / DP, d = i % DP;
    float v = (e < D_ && d < D_) ? W[e * D_ + d] : 0.f;
    Wb[i] = f2b(v);
}

// ---------------- K2: y (b,t,d f32) -> yT (b,d,t bf16), d padded to 304 ----
// Skips tiles whose 64 t-rows are ALL masked (yT for those rows is never
// consumed: attn skips fully-masked 32-tiles, which partition these 64 rows).
__global__ __launch_bounds__(256) void k_ytrans(const float* __restrict__ Y,
        const int* __restrict__ mask, unsigned short* __restrict__ yT){
    __shared__ float tile[64][65];
    const int bid = blockIdx.x;           // 64 * 16 * 5
    const int b  = bid / 80;
    const int tt = (bid % 80) / 5;
    const int dt = bid % 5;
    const int t0 = tt * 64, d0 = dt * 64;
    const int tid = threadIdx.x;
    const int dl = tid & 63, qq = tid >> 6;

    // uniform across waves: every wave reads the same 64 mask ints
    const int mv = mask[b * LY_ + t0 + dl];
    if (__all(mv != 0)) return;

    #pragma unroll
    for (int r = 0; r < 16; ++r){
        const int tl = qq * 16 + r;
        const int d = d0 + dl;
        float v = (d < D_) ? Y[((long)b * LY_ + t0 + tl) * D_ + d] : 0.f;
        tile[tl][dl] = v;
    }
    __syncthreads();
    #pragma unroll
    for (int r = 0; r < 16; ++r){
        const int drow = d0 + qq * 16 + r;
        if (drow < DV){
            float v = (drow < D_) ? tile[dl][qq * 16 + r] : 0.f;
            yT[((long)b * DV + drow) * LY_ + t0 + dl] = f2b(v);
        }
    }
}

// ---------------- K1: proj = relu(Z @ W^T + b), swapped-operand epilogue ----
// y-half: per-wave skip when all 32 rows of the wave's tile are masked
// (y_proj of masked rows only feeds masked-out scores).
__global__ __launch_bounds__(256) void k_proj(const float* __restrict__ X,
        const float* __restrict__ Y, const float* __restrict__ bias,
        const int* __restrict__ mask, const unsigned short* __restrict__ Wb,
        unsigned short* __restrict__ Px, unsigned short* __restrict__ Py){
    const int tid = threadIdx.x;
    const int w = tid >> 6, l = tid & 63;
    const int lr = l & 15, lg = l >> 4;
    const long m0 = (long)blockIdx.x * 128;
    const bool isX = (m0 < (long)B_ * LX_);
    const float* S = isX ? X : Y;
    unsigned short* Dst = isX ? Px : Py;
    const long base = isX ? m0 : m0 - (long)B_ * LX_;

    if (!isX){
        // rows base+32w .. base+32w+31 (one batch; lanes 32-63 mirror 0-31)
        const int bb = (int)(base >> 10);
        const int trow = ((int)base & 1023) + 32 * w + (l & 31);
        const int mv = mask[bb * LY_ + trow];
        if (__all(mv != 0)) return;           // whole wave-tile masked: skip
    }

    u32x4 a[2][10];
    #pragma unroll
    for (int ms = 0; ms < 2; ++ms){
        const float* rp = S + (base + 32 * w + 16 * ms + lr) * D_;
        #pragma unroll
        for (int ks = 0; ks < 10; ++ks){
            const int k0 = ks * 32 + lg * 8;
            f32x4 v0 = {0,0,0,0}, v1 = {0,0,0,0};
            if (k0 + 4 <= D_) v0 = *(const f32x4*)(rp + k0);
            if (k0 + 8 <= D_) v1 = *(const f32x4*)(rp + k0 + 4);
            u32x4 u;
            u[0] = pk_bf16(v0[0], v0[1]);
            u[1] = pk_bf16(v0[2], v0[3]);
            u[2] = pk_bf16(v1[0], v1[1]);
            u[3] = pk_bf16(v1[2], v1[3]);
            a[ms][ks] = u;
        }
    }

    #pragma unroll 2
    for (int es = 0; es < 20; ++es){
        f32x4 acc0 = {0,0,0,0}, acc1 = {0,0,0,0};
        const unsigned short* wp = Wb + (es * 16 + lr) * DP + lg * 8;
        #pragma unroll
        for (int ks = 0; ks < 10; ++ks){
            bf16x8 bf = ld_bf8(wp + ks * 32);       // A: row=e, k=d
            acc0 = mfma16(bf, __builtin_bit_cast(bf16x8, a[0][ks]), acc0);
            acc1 = mfma16(bf, __builtin_bit_cast(bf16x8, a[1][ks]), acc1);
        }
        // lane holds D[e = es*16 + 4*lg + r][m = lr]
        const int e0 = es * 16 + lg * 4;
        f32x4 bv = {0,0,0,0};
        if (e0 + 4 <= D_) bv = *(const f32x4*)(bias + e0);
        else {
            #pragma unroll
            for (int r = 0; r < 4; ++r) bv[r] = (e0 + r < D_) ? bias[e0 + r] : 0.f;
        }
        float s0[4], s1[4];
        #pragma unroll
        for (int r = 0; r < 4; ++r){
            float t0v = acc0[r] + bv[r]; s0[r] = t0v > 0.f ? t0v : 0.f;
            float t1v = acc1[r] + bv[r]; s1[r] = t1v > 0.f ? t1v : 0.f;
        }
        const u32x2 o0 = { pk_bf16(s0[0], s0[1]), pk_bf16(s0[2], s0[3]) };
        const u32x2 o1 = { pk_bf16(s1[0], s1[1]), pk_bf16(s1[2], s1[3]) };
        *(u32x2*)(Dst + (base + 32 * w + lr) * DP + e0)      = o0;
        *(u32x2*)(Dst + (base + 32 * w + 16 + lr) * DP + e0) = o1;
    }
}

// ---------------- K3: flash attention (r4 structure + swizzled linear LDS) --
// mask is int32: 0 = keep, nonzero = masked out
__global__ __launch_bounds__(256, 2) void k_attn(const int* __restrict__ mask,
        const unsigned short* __restrict__ Px, const unsigned short* __restrict__ Py,
        const unsigned short* __restrict__ yT, float* __restrict__ out){
    __shared__ unsigned short Yp_lds[KV][320];   // linear; XOR-swizzled write/read
    __shared__ unsigned short yT_lds[DV][32];    // linear; XOR-swizzled write/read
    __shared__ unsigned short P_lds[BM][40];     // padded (ds-written, as r4)

    const int tid = threadIdx.x;
    const int w = tid >> 6, l = tid & 63;
    const int lr = l & 15, lg = l >> 4;
    const int sw3 = lr & 7;          // Yp read swizzle: chunk ^= sw3
    const int s2  = (lr >> 1) & 3;   // yT read swizzle: chunk ^= s2

    // XCD-bijective swizzle: all 16 s-blocks of a batch land on one XCD
    const int bid = blockIdx.x;              // 1024
    const int xcd = bid & 7;
    const int g = bid >> 3;
    const int b = xcd + 8 * (g >> 4);
    const int s0 = (g & 15) * BM;

    // Q fragments: wave w owns rows s0+16w .. s0+16w+15 (B-operand: col = lr)
    u32x4 q[10];
    {
        const unsigned short* qp = Px + ((long)b * LX_ + s0 + 16 * w + lr) * DP + lg * 8;
        #pragma unroll
        for (int ks = 0; ks < 10; ++ks) q[ks] = *(const u32x4*)(qp + ks * 32);
    }

    // ---- staging address setup (loop-invariant; dst chunk XOR-swizzled) ----
    const unsigned short* srcYp[5];
    unsigned short*       dstYp[5];
    #pragma unroll
    for (int j = 0; j < 5; ++j){
        const int id = tid + 256 * j;            // 0..1279
        const int row = id / 40, c = id % 40;
        srcYp[j] = Py + ((long)b * LY_ + row) * DP + c * 8;
        dstYp[j] = &Yp_lds[row][(c ^ (row & 7)) * 8];
    }
    const unsigned short* srcYT[5];
    unsigned short*       dstYT[5];
    #pragma unroll
    for (int j = 0; j < 5; ++j){
        const int id = tid + 256 * j;            // valid if < 1216
        const int row = (id >> 2) < DV ? (id >> 2) : (DV - 1);
        const int c = id & 3;
        srcYT[j] = yT + ((long)b * DV + row) * LY_ + c * 8;
        dstYT[j] = &yT_lds[row][(c ^ ((row >> 1) & 3)) * 8];
    }
    const bool v4 = (tid < 192);                 // j=4 validity for yT chunks

    const int* mrow = mask + (long)b * LY_;

    // ---- prologue: stage tile 0 ----
    u32x4 pA[5], pT[5];
    #pragma unroll
    for (int j = 0; j < 5; ++j) pA[j] = *(const u32x4*)srcYp[j];
    #pragma unroll
    for (int j = 0; j < 4; ++j) pT[j] = *(const u32x4*)srcYT[j];
    if (v4) pT[4] = *(const u32x4*)srcYT[4];
    int4 m0v = *(const int4*)(mrow + lg * 4);
    int4 m1v = *(const int4*)(mrow + 16 + lg * 4);
    #pragma unroll
    for (int j = 0; j < 5; ++j) *(u32x4*)dstYp[j] = pA[j];
    #pragma unroll
    for (int j = 0; j < 4; ++j) *(u32x4*)dstYT[j] = pT[j];
    if (v4) *(u32x4*)dstYT[4] = pT[4];
    __syncthreads();

    f32x4 acc[19];
    #pragma unroll
    for (int n = 0; n < 19; ++n) acc[n] = f32x4{0,0,0,0};
    float m_r = -INFINITY;    // running max for s-row = s0+16w+lr
    float l_r = 0.f;

    for (int it = 0; it < NT; ++it){
        const bool notlast = (it < NT - 1);

        // ---- A: issue next tile's global loads (consumed after barrier) ----
        int4 mn0, mn1;
        if (notlast){
            #pragma unroll
            for (int j = 0; j < 5; ++j){ srcYp[j] += KV * DP; pA[j] = *(const u32x4*)srcYp[j]; }
            #pragma unroll
            for (int j = 0; j < 4; ++j){ srcYT[j] += KV;      pT[j] = *(const u32x4*)srcYT[j]; }
            srcYT[4] += KV;
            if (v4) pT[4] = *(const u32x4*)srcYT[4];
            mn0 = *(const int4*)(mrow + (it + 1) * KV + lg * 4);
            mn1 = *(const int4*)(mrow + (it + 1) * KV + 16 + lg * 4);
        }

        // ---- B: compute on current tile (skip if fully masked) ----
        const int allm = (m0v.x && m0v.y && m0v.z && m0v.w &&
                          m1v.x && m1v.y && m1v.z && m1v.w) ? 1 : 0;
        if (!__all(allm)){
            // S^T = Yp @ Q^T : lane holds S[t = it*KV+16*sub+4*lg+r][s = s0+16w+lr]
            f32x4 sv0 = {0,0,0,0}, sv1 = {0,0,0,0};
            #pragma unroll
            for (int ks = 0; ks < 10; ++ks){
                const int cc = (((ks << 2) | lg) ^ sw3) << 3;   // swizzled u16 col
                bf16x8 qf = __builtin_bit_cast(bf16x8, q[ks]);
                bf16x8 a0 = ld_bf8(&Yp_lds[lr][cc]);
                bf16x8 a1 = ld_bf8(&Yp_lds[16 + lr][cc]);
                sv0 = mfma16(a0, qf, sv0);
                sv1 = mfma16(a1, qf, sv1);
            }

            float v0[4], v1[4];
            v0[0] = sv0[0] + (m0v.x ? -3.0e38f : 0.f);
            v0[1] = sv0[1] + (m0v.y ? -3.0e38f : 0.f);
            v0[2] = sv0[2] + (m0v.z ? -3.0e38f : 0.f);
            v0[3] = sv0[3] + (m0v.w ? -3.0e38f : 0.f);
            v1[0] = sv1[0] + (m1v.x ? -3.0e38f : 0.f);
            v1[1] = sv1[1] + (m1v.y ? -3.0e38f : 0.f);
            v1[2] = sv1[2] + (m1v.z ? -3.0e38f : 0.f);
            v1[3] = sv1[3] + (m1v.w ? -3.0e38f : 0.f);

            float mx = fmaxf(fmaxf(fmaxf(v0[0], v0[1]), fmaxf(v0[2], v0[3])),
                             fmaxf(fmaxf(v1[0], v1[1]), fmaxf(v1[2], v1[3])));
            mx = fmaxf(mx, __shfl_xor(mx, 16));
            mx = fmaxf(mx, __shfl_xor(mx, 32));
            const float nm = fmaxf(m_r, mx);

            float p0[4], p1[4];
            float ps = 0.f;
            #pragma unroll
            for (int r = 0; r < 4; ++r){
                p0[r] = __expf(v0[r] - nm);
                p1[r] = __expf(v1[r] - nm);
                ps += p0[r] + p1[r];
            }
            ps += __shfl_xor(ps, 16);
            ps += __shfl_xor(ps, 32);
            const float sc = __expf(m_r - nm);   // first tile: exp(-inf)=0
            l_r = l_r * sc + ps;
            m_r = nm;

            // rescale acc rows (s = 4*lg + r): broadcast sc from lane 4*lg+r
            float scr[4];
            #pragma unroll
            for (int r = 0; r < 4; ++r) scr[r] = __shfl(sc, lg * 4 + r);
            #pragma unroll
            for (int n = 0; n < 19; ++n){
                #pragma unroll
                for (int r = 0; r < 4; ++r) acc[n][r] *= scr[r];
            }

            // pack P -> bf16, write own wave's rows (within-wave dependency only)
            const unsigned c00 = pk_bf16(p0[0], p0[1]);
            const unsigned c01 = pk_bf16(p0[2], p0[3]);
            const unsigned c10 = pk_bf16(p1[0], p1[1]);
            const unsigned c11 = pk_bf16(p1[2], p1[3]);
            *(u32x2*)&P_lds[16 * w + lr][4 * lg]      = u32x2{c00, c01};
            *(u32x2*)&P_lds[16 * w + lr][16 + 4 * lg] = u32x2{c10, c11};

            // O += P @ y (yT read with swizzled chunk)
            bf16x8 pf = ld_bf8(&P_lds[16 * w + lr][lg * 8]);
            const int vcc = (lg ^ s2) << 3;
            #pragma unroll
            for (int n = 0; n < 19; ++n){
                bf16x8 vf = ld_bf8(&yT_lds[n * 16 + lr][vcc]);
                acc[n] = mfma16(pf, vf, acc[n]);
            }
        }

        __syncthreads();           // all waves done reading LDS
        if (notlast){
            #pragma unroll
            for (int j = 0; j < 5; ++j) *(u32x4*)dstYp[j] = pA[j];
            #pragma unroll
            for (int j = 0; j < 4; ++j) *(u32x4*)dstYT[j] = pT[j];
            if (v4) *(u32x4*)dstYT[4] = pT[4];
            m0v = mn0; m1v = mn1;
        }
        __syncthreads();           // LDS ready for next iteration
    }

    // normalize: 1/l for rows s = 4*lg + r via broadcast
    const float il = 1.f / l_r;
    float invr[4];
    #pragma unroll
    for (int r = 0; r < 4; ++r) invr[r] = __shfl(il, lg * 4 + r);

    #pragma unroll
    for (int n = 0; n < 19; ++n){
        const int d = n * 16 + lr;
        if (d < D_){
            #pragma unroll
            for (int r = 0; r < 4; ++r){
                out[((long)b * LX_ + s0 + 16 * w + lg * 4 + r) * D_ + d] = acc[n][r] * invr[r];
            }
        }
    }
}

extern "C" void kernel_launch(void* const* d_in, const int* in_sizes, int n_in,
                              void* d_out, int out_size, void* d_ws, size_t ws_size,
                              hipStream_t stream){
    const float* x = (const float*)d_in[0];
    const float* y = (const float*)d_in[1];
    const int* ymask = (const int*)d_in[2];
    const float* W = (const float*)d_in[3];
    const float* bias = (const float*)d_in[4];
    float* out = (float*)d_out;

    unsigned short* Wb  = (unsigned short*)d_ws;
    unsigned short* Px  = (unsigned short*)((char*)d_ws + (1 << 18));
    unsigned short* Py  = (unsigned short*)((char*)d_ws + (1 << 18) + 41943040LL);
    unsigned short* yTw = (unsigned short*)((char*)d_ws + (1 << 18) + 83886080LL);

    hipLaunchKernelGGL(k_wconv, dim3((DP * DP + 255) / 256), dim3(256), 0, stream, W, Wb);
    hipLaunchKernelGGL(k_proj,  dim3(1024), dim3(256), 0, stream, x, y, bias, ymask, Wb, Px, Py);
    hipLaunchKernelGGL(k_ytrans, dim3(64 * 80), dim3(256), 0, stream, y, ymask, yTw);
    hipLaunchKernelGGL(k_attn,  dim3(1024), dim3(256), 0, stream, ymask, Px, Py, yTw, out);
}